// Round 1
// 2166.530 us; speedup vs baseline: 1.0994x; 1.0994x over previous
//
#include <hip/hip_runtime.h>

using bf16x8 = __attribute__((ext_vector_type(8))) short;
using f32x4  = __attribute__((ext_vector_type(4))) float;

__device__ inline float bf2f(unsigned short h){
  union { unsigned int u; float f; } v; v.u = ((unsigned int)h) << 16; return v.f;
}
__device__ inline unsigned short f2b(float x){
  union { float f; unsigned int u; } v; v.f = x;
  unsigned int r = (v.u + 0x7FFFu + ((v.u >> 16) & 1u)) >> 16;
  return (unsigned short)r;
}
__device__ inline float blo(unsigned int u){ union{unsigned int v; float f;} t; t.v = u << 16; return t.f; }
__device__ inline float bhi(unsigned int u){ union{unsigned int v; float f;} t; t.v = u & 0xffff0000u; return t.f; }

// ---------------------------------------------------------------------------
// fp32 -> bf16 bulk convert (n multiple of 4)
__global__ void conv_k(const float* __restrict__ s, unsigned short* __restrict__ d, int n){
  int i = (blockIdx.x * 256 + threadIdx.x) * 4;
  if (i >= n) return;
  float4 v = *(const float4*)(s + i);
  unsigned int p0 = (unsigned int)f2b(v.x) | ((unsigned int)f2b(v.y) << 16);
  unsigned int p1 = (unsigned int)f2b(v.z) | ((unsigned int)f2b(v.w) << 16);
  *(uint2*)(d + i) = make_uint2(p0, p1);
}

// W_dec (256x512 f32) -> WdecT (512x256 bf16, k-major). Coalesced writes.
__global__ void wdect_k(const float* __restrict__ Wd, unsigned short* __restrict__ o){
  int idx = blockIdx.x * 256 + threadIdx.x;   // idx = k*256 + a
  int k = idx >> 8, a = idx & 255;
  o[idx] = f2b(Wd[a * 512 + k]);
}

// embedding gather (pad_idx=2 -> 0), rows m = t*64+b, bf16 out
__global__ void embed_k(const int* __restrict__ tgt, const float* __restrict__ emb,
                        unsigned short* __restrict__ out, int n){
  int idx = blockIdx.x * 256 + threadIdx.x;
  if (idx >= n) return;
  int d = idx & 511, m = idx >> 9, t = m >> 6, b = m & 63;
  int tok = tgt[b * 32 + t];
  float v = (tok == 2) ? 0.f : emb[(long)tok * 512 + d];
  out[idx] = f2b(v);
}

// ---------------------------------------------------------------------------
// Generic bf16 MFMA GEMM: C[m][n] = sum_k A[m][k]*B[n][k] (+bias[n])
#define EPI_PLAIN 0
#define EPI_TANH  1
#define EPI_OUT   2
#define EPI_B16   3

template<int EPI, bool AF32>
__global__ __launch_bounds__(256)
void gemm_bt(const void* __restrict__ Av, int lda,
             const unsigned short* __restrict__ Bp, int ldb,
             const float* __restrict__ bias,
             float* __restrict__ Cf, unsigned short* __restrict__ Cb, int ldc,
             int K,
             int n_split, const void* __restrict__ A2v,
             const unsigned short* __restrict__ B2p, int lda2, int ldb2)
{
  __shared__ __align__(16) unsigned short As[64][40];
  __shared__ __align__(16) unsigned short Bs[256][40];

  int m0 = blockIdx.x * 64;
  int n0 = blockIdx.y * 256;
  const void* Ap = Av; const unsigned short* Bq = Bp;
  int la = lda, lb = ldb, nB = n0;
  if (n_split > 0 && n0 >= n_split){ Ap = A2v; Bq = B2p; la = lda2; lb = ldb2; nB = n0 - n_split; }

  int tid  = threadIdx.x;
  int wave = tid >> 6, lane = tid & 63, quad = lane >> 4, lrow = lane & 15;

  f32x4 acc[4][4];
#pragma unroll
  for (int i = 0; i < 4; ++i)
#pragma unroll
    for (int j = 0; j < 4; ++j)
#pragma unroll
      for (int r = 0; r < 4; ++r) acc[i][j][r] = 0.f;

  int ar = tid >> 2, ac = (tid & 3) * 8;

  for (int k0 = 0; k0 < K; k0 += 32){
    if (AF32){
      const float* A32 = (const float*)Ap;
      const float4* src = (const float4*)(A32 + (long)(m0 + ar) * la + k0 + ac);
      float4 x0 = src[0], x1 = src[1];
      unsigned int p0 = (unsigned int)f2b(x0.x) | ((unsigned int)f2b(x0.y) << 16);
      unsigned int p1 = (unsigned int)f2b(x0.z) | ((unsigned int)f2b(x0.w) << 16);
      unsigned int p2 = (unsigned int)f2b(x1.x) | ((unsigned int)f2b(x1.y) << 16);
      unsigned int p3 = (unsigned int)f2b(x1.z) | ((unsigned int)f2b(x1.w) << 16);
      *(uint4*)&As[ar][ac] = make_uint4(p0, p1, p2, p3);
    } else {
      const unsigned short* A16 = (const unsigned short*)Ap;
      *(uint4*)&As[ar][ac] = *(const uint4*)(A16 + (long)(m0 + ar) * la + k0 + ac);
    }
#pragma unroll
    for (int c = 0; c < 4; ++c){
      int id = tid + c * 256; int br = id >> 2, bc = (id & 3) * 8;
      *(uint4*)&Bs[br][bc] = *(const uint4*)(Bq + (long)(nB + br) * lb + k0 + bc);
    }
    __syncthreads();

    bf16x8 af[4], bfr[4];
#pragma unroll
    for (int mf = 0; mf < 4; ++mf) af[mf]  = *(const bf16x8*)&As[mf * 16 + lrow][quad * 8];
#pragma unroll
    for (int nf = 0; nf < 4; ++nf) bfr[nf] = *(const bf16x8*)&Bs[wave * 64 + nf * 16 + lrow][quad * 8];
#pragma unroll
    for (int mf = 0; mf < 4; ++mf)
#pragma unroll
      for (int nf = 0; nf < 4; ++nf)
        acc[mf][nf] = __builtin_amdgcn_mfma_f32_16x16x32_bf16(af[mf], bfr[nf], acc[mf][nf], 0, 0, 0);
    __syncthreads();
  }

#pragma unroll
  for (int mf = 0; mf < 4; ++mf){
#pragma unroll
    for (int nf = 0; nf < 4; ++nf){
#pragma unroll
      for (int r = 0; r < 4; ++r){
        int m = m0 + mf * 16 + quad * 4 + r;
        int n = n0 + wave * 64 + nf * 16 + lrow;
        float v = acc[mf][nf][r];
        if (bias) v += bias[n];
        if (EPI == EPI_TANH){
          v = tanhf(v);
          Cf[(long)m * ldc + n] = v;
          Cb[(long)m * ldc + n] = f2b(v);
        } else if (EPI == EPI_OUT){
          Cf[(long)(m & 63) * (31 * 32000) + (long)(m >> 6) * 32000 + n] = v;
        } else if (EPI == EPI_B16){
          Cb[(long)m * ldc + n] = f2b(v);
        } else {
          Cf[(long)m * ldc + n] = v;
        }
      }
    }
  }
}

// ---------------------------------------------------------------------------
// Per-step fused kernel: GRU gates (t>0) -> h_t, then Bahdanau attention.
// 1 block / batch, 512 threads, ~114 KB LDS (1 block/CU by design; grid=64).
// All heavy reads are coalesced: enc_proj tile staged to swizzled LDS,
// W_dec consumed k-major, enc_out consumed as packed bf16 pairs.
__global__ __launch_bounds__(512)
void attn_step(const uint4* __restrict__ ep4,        // enc_proj bf16 [(b*196+s)*256+a]
               const unsigned int* __restrict__ eo2, // enc_out bf16 pairs [(b*196+s)*256 + e/2]
               const float* __restrict__ W_score,
               const float* __restrict__ b_dec,
               const float* __restrict__ b_hh,
               const float* __restrict__ gi_emb,
               const float* __restrict__ giq,
               float* __restrict__ h_all,
               unsigned short* __restrict__ h_b16,
               const uint2* __restrict__ WdecT4,     // bf16 [k][a], uint2 = 4 a-values
               unsigned short* __restrict__ ctx_b16,
               int t, int do_gates, int do_attn)
{
  __shared__ __align__(16) uint4 ep_s4[6272];  // 196 rows x 32 chunks, XOR-swizzled
  __shared__ float sh_h[512];
  __shared__ float2 dpw[256];                  // {dec_proj[a], W_score[a]}
  __shared__ float spart[2048];                // partials (dec_proj / scores / ctx)
  __shared__ float sw[256];
  __shared__ float wred[16];

  int b = blockIdx.x, tid = threadIdx.x;
  int lane = tid & 63, wv = tid >> 6;

  // ---- GRU gates for h_t ----
  float hv;
  if (do_gates){
    int j = tid;
    long ge = ((long)(t - 1) * 64 + b) * 1536;
    long gq = (long)b * 3072;
    float gir = gi_emb[ge + j]        + giq[gq + j];
    float giz = gi_emb[ge + 512 + j]  + giq[gq + 512 + j];
    float gin = gi_emb[ge + 1024 + j] + giq[gq + 1024 + j];
    float ghr = giq[gq + 1536 + j]        + b_hh[j];
    float ghz = giq[gq + 1536 + 512 + j]  + b_hh[512 + j];
    float ghn = giq[gq + 1536 + 1024 + j] + b_hh[1024 + j];
    float rr = 1.f / (1.f + __expf(-(gir + ghr)));
    float zz = 1.f / (1.f + __expf(-(giz + ghz)));
    float nn = tanhf(gin + rr * ghn);
    float hp = h_all[((long)(t - 1) * 64 + b) * 512 + j];
    hv = (1.f - zz) * nn + zz * hp;
    h_all[((long)t * 64 + b) * 512 + j] = hv;
    h_b16[((long)t * 64 + b) * 512 + j] = f2b(hv);
  } else {
    hv = h_all[((long)t * 64 + b) * 512 + tid];
  }
  if (!do_attn) return;   // uniform

  sh_h[tid] = hv;
  float wsc = (tid < 256) ? W_score[tid] : 0.f;

  // ---- stage enc_proj[b] (196x256 bf16 = 98 KB) into LDS, chunk-XOR swizzle ----
  // chunk index = row*32 + (col ^ (row&7)): 8 consecutive rows land in 8
  // distinct 16B slots -> conflict-free ds_read_b128 at row-stride 512 B.
  {
    const uint4* src = ep4 + (long)b * 6272;
    for (int c = tid; c < 6272; c += 512){
      int r = c >> 5, col = c & 31;
      ep_s4[(r << 5) | (col ^ (r & 7))] = src[c];
    }
  }
  __syncthreads();

  // ---- dec_proj[a] = h . W_dec[a,:] + b_dec[a] (coalesced k-major GEMV) ----
  {
    int a4 = tid & 63, kg = tid >> 6;             // 64 a-quads x 8 k-groups
    const uint2* wp = WdecT4 + ((kg << 12) | a4); // (kg*64+kk)*64 + a4
    const float* hp = &sh_h[kg << 6];
    float ac0 = 0.f, ac1 = 0.f, ac2 = 0.f, ac3 = 0.f;
#pragma unroll 16
    for (int kk = 0; kk < 64; ++kk){
      uint2 wq = wp[kk << 6];
      float hk = hp[kk];
      ac0 += hk * blo(wq.x); ac1 += hk * bhi(wq.x);
      ac2 += hk * blo(wq.y); ac3 += hk * bhi(wq.y);
    }
    *(float4*)&spart[(kg << 8) | (a4 << 2)] = make_float4(ac0, ac1, ac2, ac3);
  }
  __syncthreads();
  if (tid < 256){
    float dp = b_dec[tid];
#pragma unroll
    for (int kg = 0; kg < 8; ++kg) dp += spart[(kg << 8) | tid];
    dpw[tid] = make_float2(dp, wsc);
  }
  __syncthreads();

  // ---- scores[s] = sum_a wsc[a]*tanh(ep[s][a]+dp[a]); a split over 2 halves ----
  {
    int s = tid & 255, half = tid >> 8;
    float acc = 0.f;
    if (s < 196){
      int rb = s << 5, sx = s & 7;
#pragma unroll 4
      for (int j = 0; j < 16; ++j){
        uint4 v = ep_s4[rb | (((half << 4) | j) ^ sx)];
        int aj = (half << 7) | (j << 3);
#define SCP(uu, ab) { \
        float2 dA = dpw[ab], dB = dpw[(ab) + 1]; \
        float xA = blo(uu) + dA.x, xB = bhi(uu) + dB.x; \
        float eA = __expf(2.f * xA), eB = __expf(2.f * xB); \
        acc += dA.y * (1.f - 2.f / (eA + 1.f)); \
        acc += dB.y * (1.f - 2.f / (eB + 1.f)); }
        SCP(v.x, aj) SCP(v.y, aj + 2) SCP(v.z, aj + 4) SCP(v.w, aj + 6)
#undef SCP
      }
    }
    spart[tid] = acc;
  }
  __syncthreads();

  // ---- softmax over s (196): shfl butterfly + 4-entry LDS combine ----
  float sc = -1e30f, ee = 0.f;
  if (tid < 256) sc = (tid < 196) ? (spart[tid] + spart[tid + 256]) : -1e30f;
  float mm = sc;
#pragma unroll
  for (int off = 32; off >= 1; off >>= 1) mm = fmaxf(mm, __shfl_xor(mm, off));
  if (tid < 256 && lane == 0) wred[wv] = mm;
  __syncthreads();
  float mx = fmaxf(fmaxf(wred[0], wred[1]), fmaxf(wred[2], wred[3]));
  if (tid < 256){
    ee = (tid < 196) ? __expf(sc - mx) : 0.f;
    sw[tid] = ee;                                 // unnormalized; fold 1/sum at end
  }
  float ss = ee;
#pragma unroll
  for (int off = 32; off >= 1; off >>= 1) ss += __shfl_xor(ss, off);
  if (tid < 256 && lane == 0) wred[8 + wv] = ss;
  __syncthreads();
  float inv = 1.f / (wred[8] + wred[9] + wred[10] + wred[11]);

  // ---- context[e] = inv * sum_s sw[s]*enc_out[b,s,e]; e-pairs x 2 s-halves ----
  {
    int e2 = tid & 255, sh2 = tid >> 8;
    const unsigned int* src = eo2 + ((long)b * 196 + sh2 * 98) * 256 + e2;
    float a0 = 0.f, a1 = 0.f;
#pragma unroll 2
    for (int s2 = 0; s2 < 98; ++s2){
      unsigned int v = src[(long)s2 * 256];
      float w = sw[sh2 * 98 + s2];
      a0 += w * blo(v); a1 += w * bhi(v);
    }
    *(float2*)&spart[(sh2 << 9) | (e2 << 1)] = make_float2(a0, a1);
  }
  __syncthreads();
  {
    float cv = (spart[tid] + spart[tid + 512]) * inv;
    ctx_b16[(b << 9) | tid] = f2b(cv);
  }
}

// ---------------------------------------------------------------------------
extern "C" void kernel_launch(void* const* d_in, const int* in_sizes, int n_in,
                              void* d_out, int out_size, void* d_ws, size_t ws_size,
                              hipStream_t stream)
{
  (void)in_sizes; (void)n_in; (void)out_size; (void)ws_size;
  const float* encoder_out = (const float*)d_in[0];
  const float* pooled      = (const float*)d_in[1];
  const int*   targets     = (const int*)d_in[2];
  const float* embedding   = (const float*)d_in[3];
  const float* W_enc  = (const float*)d_in[4];
  const float* b_enc  = (const float*)d_in[5];
  const float* W_dec  = (const float*)d_in[6];
  const float* b_dec  = (const float*)d_in[7];
  const float* W_score= (const float*)d_in[8];
  const float* W_ih   = (const float*)d_in[10];
  const float* W_hh   = (const float*)d_in[11];
  const float* b_ih   = (const float*)d_in[12];
  const float* b_hh   = (const float*)d_in[13];
  const float* W_out  = (const float*)d_in[14];
  const float* b_out  = (const float*)d_in[15];
  const float* W_init = (const float*)d_in[16];
  const float* b_init = (const float*)d_in[17];
  float* out = (float*)d_out;

  char* w = (char*)d_ws;
  unsigned short* eo_b16  = (unsigned short*)w; w += 12845056;  // 64*196*512 bf16 (reuses old enc_proj f32 slot size)
  float* gi_emb           = (float*)w;          w += 12189696;  // 31*64*1536 f32
  float* h_all            = (float*)w;          w += 4194304;   // 32*64*512 f32
  unsigned short* h_b16   = (unsigned short*)w; w += 2097152;   // 32*64*512 bf16
  float* giq              = (float*)w;          w += 786432;    // 64*3072 f32
  unsigned short* ctx_b16 = (unsigned short*)w; w += 65536;     // 64*512 bf16
  unsigned short* emb_b16 = (unsigned short*)w; w += 2031616;   // 1984*512 bf16
  unsigned short* Wout_b  = (unsigned short*)w; w += 32768000;
  unsigned short* Wih_b   = (unsigned short*)w; w += 3145728;
  unsigned short* Whh_b   = (unsigned short*)w; w += 1572864;
  unsigned short* WdecT_b = (unsigned short*)w; w += 262144;    // 512x256 bf16 k-major
  unsigned short* Winit_b = (unsigned short*)w; w += 524288;
  unsigned short* Wenc_b  = (unsigned short*)w; w += 262144;
  unsigned short* ep_b16  = (unsigned short*)w; w += 6422528;   // 64*196*256 bf16 (new)

  auto conv = [&](const float* s, unsigned short* d, int n){
    conv_k<<<dim3((n / 4 + 255) / 256), dim3(256), 0, stream>>>(s, d, n);
  };
  conv(W_out,  Wout_b,  32000 * 512);
  conv(W_ih,   Wih_b,   1536 * 1024);
  conv(W_hh,   Whh_b,   1536 * 512);
  conv(W_init, Winit_b, 512 * 512);
  conv(W_enc,  Wenc_b,  256 * 512);
  conv(encoder_out, eo_b16, 64 * 196 * 512);
  wdect_k<<<dim3(512), dim3(256), 0, stream>>>(W_dec, WdecT_b);
  embed_k<<<dim3((1984 * 512) / 256), dim3(256), 0, stream>>>(targets, embedding, emb_b16, 1984 * 512);

  // h0 = tanh(pooled @ W_init^T + b_init)
  gemm_bt<EPI_TANH, true><<<dim3(1, 2), 256, 0, stream>>>(
      pooled, 512, Winit_b, 512, b_init, h_all, h_b16, 512, 512, 0, nullptr, nullptr, 0, 0);
  // enc_proj (bf16 direct) = encoder_out @ W_enc^T + b_enc  (M=12544)
  gemm_bt<EPI_B16, true><<<dim3(196, 1), 256, 0, stream>>>(
      encoder_out, 512, Wenc_b, 512, b_enc, nullptr, ep_b16, 256, 512, 0, nullptr, nullptr, 0, 0);
  // gi_emb = embedded @ W_ih[:, :512]^T + b_ih  (M=1984)
  gemm_bt<EPI_PLAIN, false><<<dim3(31, 6), 256, 0, stream>>>(
      emb_b16, 512, Wih_b, 1024, b_ih, gi_emb, nullptr, 1536, 512, 0, nullptr, nullptr, 0, 0);

  for (int t = 0; t < 31; ++t){
    attn_step<<<dim3(64), dim3(512), 0, stream>>>(
        (const uint4*)ep_b16, (const unsigned int*)eo_b16, W_score, b_dec, b_hh,
        gi_emb, giq, h_all, h_b16, (const uint2*)WdecT_b, ctx_b16,
        t, (t > 0) ? 1 : 0, 1);
    // giq[:, 0:1536] = W_ih[:,512:] . ctx ; giq[:, 1536:3072] = W_hh . h_t
    gemm_bt<EPI_PLAIN, false><<<dim3(1, 12), 256, 0, stream>>>(
        ctx_b16, 512, Wih_b + 512, 1024, nullptr, giq, nullptr, 3072, 512,
        1536, h_b16 + (long)t * 64 * 512, Whh_b, 512, 512);
  }
  // final gates: h_31
  attn_step<<<dim3(64), dim3(512), 0, stream>>>(
      (const uint4*)ep_b16, (const unsigned int*)eo_b16, W_score, b_dec, b_hh,
      gi_emb, giq, h_all, h_b16, (const uint2*)WdecT_b, ctx_b16, 31, 1, 0);

  // logits: (1984 x 32000 x 512), A = h_1..h_31, scatter to (b,t,v)
  gemm_bt<EPI_OUT, false><<<dim3(31, 125), 256, 0, stream>>>(
      h_b16 + 64 * 512, 512, Wout_b, 512, b_out, out, nullptr, 0, 512,
      0, nullptr, nullptr, 0, 0);
}